// Round 7
// baseline (339.247 us; speedup 1.0000x reference)
//
#include <hip/hip_runtime.h>
#include <float.h>

#define N_TOK   32768
#define DIM     64
#define K_CODES 8192
#define HWSZ    1024
#define CHW     65536
#define NELEM   2097152

typedef short  bf16x8 __attribute__((ext_vector_type(8)));
typedef float  f32x16 __attribute__((ext_vector_type(16)));

static __device__ __forceinline__ unsigned short f2bf(float x) {
    unsigned u = __float_as_uint(x);
    unsigned r = u + 0x7FFFu + ((u >> 16) & 1u);
    return (unsigned short)(r >> 16);
}
static __device__ __forceinline__ float bf2f(unsigned short h) {
    return __uint_as_float(((unsigned)h) << 16);
}

// ------- prep_e: emb -> frag-ordered bf16 hi/lo blob + ||e||^2 + ws zeroing --
__global__ __launch_bounds__(256) void prep_e(const float* __restrict__ emb,
                                              unsigned short* __restrict__ blob,
                                              float* __restrict__ eng,
                                              unsigned long long* __restrict__ packed,
                                              int* __restrict__ cnt_i,
                                              float* __restrict__ sums,
                                              int* __restrict__ ctrs) {
    __shared__ float part[512];
    const int gid = blockIdx.x * 256 + threadIdx.x;   // 0..32767
    packed[gid] = ~0ull;                              // init for atomicMin
    if (gid < K_CODES) cnt_i[gid] = 0;
    if (gid < 2) sums[gid] = 0.f;
    if (gid < 2) ctrs[gid] = 0;                       // done-counter + barrier

    int tile = blockIdx.x;
    #pragma unroll
    for (int u0 = 0; u0 < 2; ++u0) {
        int u = threadIdx.x + u0 * 256;
        int s = u >> 7, h = (u >> 6) & 1, n = u & 63;
        const float* src = emb + (tile * 64 + n) * 64 + s * 16 + h * 8;
        float4 v0 = *(const float4*)src;
        float4 v1 = *(const float4*)(src + 4);
        float x[8] = {v0.x, v0.y, v0.z, v0.w, v1.x, v1.y, v1.z, v1.w};
        unsigned short hi[8], lo[8];
        float ss = 0.f;
        #pragma unroll
        for (int j = 0; j < 8; ++j) {
            hi[j] = f2bf(x[j]);
            lo[j] = f2bf(x[j] - bf2f(hi[j]));
            ss += x[j] * x[j];
        }
        part[u] = ss;
        unsigned short* dhi = blob + (size_t)tile * 8192 + ((s * 2 + 0) * 2 + h) * 512 + n * 8;
        unsigned short* dlo = blob + (size_t)tile * 8192 + ((s * 2 + 1) * 2 + h) * 512 + n * 8;
        uint4 ph, pl;
        ph.x = (unsigned)hi[0] | ((unsigned)hi[1] << 16);
        ph.y = (unsigned)hi[2] | ((unsigned)hi[3] << 16);
        ph.z = (unsigned)hi[4] | ((unsigned)hi[5] << 16);
        ph.w = (unsigned)hi[6] | ((unsigned)hi[7] << 16);
        pl.x = (unsigned)lo[0] | ((unsigned)lo[1] << 16);
        pl.y = (unsigned)lo[2] | ((unsigned)lo[3] << 16);
        pl.z = (unsigned)lo[4] | ((unsigned)lo[5] << 16);
        pl.w = (unsigned)lo[6] | ((unsigned)lo[7] << 16);
        *(uint4*)dhi = ph;
        *(uint4*)dlo = pl;
    }
    __syncthreads();
    if (threadIdx.x < 64) {
        float s = 0.f;
        #pragma unroll
        for (int j = 0; j < 8; ++j) s += part[threadIdx.x + j * 64];
        eng[tile * 64 + threadIdx.x] = s;
    }
}

// ---------------- argmin: software-pipelined, eng-seeded acc (R4 exact) ------
// Block: 64 tokens, 4 waves. Wave wid walks half-kt tiles hk = ks*128+wid,+4.
// Body: seed acc from eng regs -> issue next eng loads -> 24 MFMA (setprio) ->
//       issue next E loads -> epilogue (cmp/sel min only).
// Loads are unconditional: last-iteration over-read lands in adjacent mapped
// workspace (eng/packed), values unused.
__global__ __launch_bounds__(256, 3) void vq_argmin(const float* __restrict__ z,
                                                    const unsigned short* __restrict__ blob,
                                                    const float* __restrict__ eng,
                                                    unsigned long long* __restrict__ packed) {
    __shared__ __align__(16) unsigned short zh[64 * 72];
    __shared__ __align__(16) unsigned short zl[64 * 72];
    __shared__ unsigned long long red[64 * 4];

    const int tid  = threadIdx.x;
    const int lane = tid & 63;
    const int wid  = tid >> 6;           // 0..3
    const int l31  = lane & 31, h = lane >> 5;

    const int tb = blockIdx.x & 511;     // token-tile id 0..511
    const int ks = blockIdx.x >> 9;      // K split 0/1
    const int n0 = tb * 64;
    const int zbase = (n0 >> 10) * CHW + (n0 & 1023);

    // ---- stage -2*z as bf16 hi/lo (64 tokens x 64 dims) ----
    {
        int f4 = tid & 15;               // 16 float4 = 64 tokens per channel
        int c0 = tid >> 4;               // 0..15
        #pragma unroll
        for (int r = 0; r < 4; ++r) {
            int c = c0 * 4 + r;
            float4 v = *(const float4*)(z + zbase + c * HWSZ + f4 * 4);
            float x[4] = {v.x, v.y, v.z, v.w};
            #pragma unroll
            for (int e = 0; e < 4; ++e) {
                int t = f4 * 4 + e;
                float xs = -2.0f * x[e];
                unsigned short hi = f2bf(xs);
                zh[t * 72 + c] = hi;
                zl[t * 72 + c] = f2bf(xs - bf2f(hi));
            }
        }
    }
    __syncthreads();

    // ---- resident token fragments (B operand), both 32-token tiles ----
    bf16x8 T0h[4], T0l[4], T1h[4], T1l[4];
    {
        int r0 = l31;        // tile 0 token
        int r1 = 32 + l31;   // tile 1 token
        #pragma unroll
        for (int s = 0; s < 4; ++s) {
            T0h[s] = *(const bf16x8*)(&zh[r0 * 72 + s * 16 + h * 8]);
            T0l[s] = *(const bf16x8*)(&zl[r0 * 72 + s * 16 + h * 8]);
            T1h[s] = *(const bf16x8*)(&zh[r1 * 72 + s * 16 + h * 8]);
            T1l[s] = *(const bf16x8*)(&zl[r1 * 72 + s * 16 + h * 8]);
        }
    }

    const int hk0 = ks * 128 + wid;
    const unsigned short* bp = blob + (size_t)(hk0 >> 1) * 8192 + ((hk0 & 1) * 32 + l31) * 8;
    const float* ep = eng + (hk0 >> 1) * 64 + (hk0 & 1) * 32 + 4 * h;
    int scode = __builtin_amdgcn_readfirstlane((hk0 >> 1) * 64 + (hk0 & 1) * 32);

    // prologue: first tile's E frags + eng
    bf16x8 Eh[4], El[4];
    #pragma unroll
    for (int s = 0; s < 4; ++s) {
        Eh[s] = *(const bf16x8*)(bp + (4 * s + h) * 512);
        El[s] = *(const bf16x8*)(bp + (4 * s + 2 + h) * 512);
    }
    float4 g0 = *(const float4*)(ep);
    float4 g1 = *(const float4*)(ep + 8);
    float4 g2 = *(const float4*)(ep + 16);
    float4 g3 = *(const float4*)(ep + 24);

    float minv0 = FLT_MAX, minv1 = FLT_MAX;
    int   mini0 = 0,       mini1 = 0;

    for (int i = 0; i < 32; ++i) {
        // seed acc with ||e||^2 (round-2 numerics: eng is the MFMA C operand)
        f32x16 ac0, ac1;
        ac0[0]  = g0.x; ac0[1]  = g0.y; ac0[2]  = g0.z; ac0[3]  = g0.w;
        ac0[4]  = g1.x; ac0[5]  = g1.y; ac0[6]  = g1.z; ac0[7]  = g1.w;
        ac0[8]  = g2.x; ac0[9]  = g2.y; ac0[10] = g2.z; ac0[11] = g2.w;
        ac0[12] = g3.x; ac0[13] = g3.y; ac0[14] = g3.z; ac0[15] = g3.w;
        ac1 = ac0;

        // prefetch next tile's eng (g regs dead after seed); whole MFMA
        // cluster + epilogue covers the latency
        ep += 128;
        g0 = *(const float4*)(ep);
        g1 = *(const float4*)(ep + 8);
        g2 = *(const float4*)(ep + 16);
        g3 = *(const float4*)(ep + 24);

        __builtin_amdgcn_s_setprio(1);
        #pragma unroll
        for (int s = 0; s < 4; ++s) {
            ac0 = __builtin_amdgcn_mfma_f32_32x32x16_bf16(El[s], T0h[s], ac0, 0, 0, 0);
            ac1 = __builtin_amdgcn_mfma_f32_32x32x16_bf16(El[s], T1h[s], ac1, 0, 0, 0);
            ac0 = __builtin_amdgcn_mfma_f32_32x32x16_bf16(Eh[s], T0l[s], ac0, 0, 0, 0);
            ac1 = __builtin_amdgcn_mfma_f32_32x32x16_bf16(Eh[s], T1l[s], ac1, 0, 0, 0);
            ac0 = __builtin_amdgcn_mfma_f32_32x32x16_bf16(Eh[s], T0h[s], ac0, 0, 0, 0);
            ac1 = __builtin_amdgcn_mfma_f32_32x32x16_bf16(Eh[s], T1h[s], ac1, 0, 0, 0);
        }
        __builtin_amdgcn_s_setprio(0);

        // prefetch next tile's E frags (E regs dead once MFMAs issued)
        bp += 2 * 8192;   // hk += 4  ->  2 kt tiles of 8192 shorts
        #pragma unroll
        for (int s = 0; s < 4; ++s) {
            Eh[s] = *(const bf16x8*)(bp + (4 * s + h) * 512);
            El[s] = *(const bf16x8*)(bp + (4 * s + 2 + h) * 512);
        }

        // epilogue: acc IS the distance; min-update (cmp + 2 sel)
        #pragma unroll
        for (int r = 0; r < 16; ++r) {
            int code = scode + ((r & 3) + 8 * (r >> 2));
            if (ac0[r] < minv0) { minv0 = ac0[r]; mini0 = code; }
            if (ac1[r] < minv1) { minv1 = ac1[r]; mini1 = code; }
        }
        scode += 128;
    }
    mini0 += 4 * h;   // lane-dependent part of code, applied once
    mini1 += 4 * h;

    // ---- merge h halves (same token, disjoint code rows), then waves ----
    unsigned u0 = __float_as_uint(minv0);
    u0 = (u0 & 0x80000000u) ? ~u0 : (u0 | 0x80000000u);
    unsigned long long k0 = ((unsigned long long)u0 << 32) | (unsigned)mini0;
    unsigned u1 = __float_as_uint(minv1);
    u1 = (u1 & 0x80000000u) ? ~u1 : (u1 | 0x80000000u);
    unsigned long long k1 = ((unsigned long long)u1 << 32) | (unsigned)mini1;
    unsigned long long o0 = __shfl_xor(k0, 32, 64);
    if (o0 < k0) k0 = o0;
    unsigned long long o1 = __shfl_xor(k1, 32, 64);
    if (o1 < k1) k1 = o1;
    if (h == 0) {
        red[l31 * 4 + wid]        = k0;
        red[(32 + l31) * 4 + wid] = k1;
    }
    __syncthreads();
    if (tid < 64) {
        unsigned long long a = red[tid * 4], b = red[tid * 4 + 1];
        unsigned long long c = red[tid * 4 + 2], d = red[tid * 4 + 3];
        unsigned long long m = (b < a) ? b : a;
        if (c < m) m = c;
        if (d < m) m = d;
        atomicMin(&packed[n0 + tid], m);
    }
}

// ------- zq_fused: zq_loss + (last block: scan_cs + scatter) -----------------
// Main body identical to the old zq_loss. The LAST block to finish (done-
// counter election, fence-before-signal) then re-reads cnt_i (atomics, L2),
// scans with 256 threads, writes csn_out/loss_out, and scatters all 32768
// tokens through an LDS cursor. Integer scan/scatter is exact; only the
// denom FP reduction order changes (~1e-7 relative, harmless).
// NOTE: code_of aliases packed — safe because the done-counter guarantees
// every block's packed reads completed before any code_of write.
__global__ __launch_bounds__(256) void zq_fused(const float* __restrict__ z,
                                                const float* __restrict__ emb,
                                                const float* __restrict__ ema_w,
                                                const float* __restrict__ csize,
                                                const unsigned long long* __restrict__ packed,
                                                float* __restrict__ zq_out,
                                                float* __restrict__ idx_out,
                                                int* __restrict__ idx_i32,
                                                int* __restrict__ cnt_i,
                                                float* __restrict__ loss_sum,
                                                float* __restrict__ z_t,
                                                float* __restrict__ emao_out,
                                                int* __restrict__ done_ctr,
                                                int* __restrict__ tok_of,
                                                int* __restrict__ code_of,
                                                float* __restrict__ csn_out,
                                                float* __restrict__ loss_out) {
    __shared__ int   curs[8192];    // 32 KB LDS cursor (last block only)
    __shared__ int   sc[256];
    __shared__ float sfr[256];
    __shared__ int   is_last;

    const int tid = threadIdx.x;
    const int n0  = blockIdx.x * 64;
    const int t   = tid >> 2, q = tid & 3;
    const int n   = n0 + t;
    const int idx = (int)(packed[n] & 0xFFFFFFFFull);
    if (q == 0) {
        idx_out[n] = (float)idx;
        idx_i32[n] = idx;
        atomicAdd(&cnt_i[idx], 1);
    }
    // emao init: 4 strided elements per thread, coalesced scalar stores
    {
        int g = blockIdx.x * 256 + tid;         // 0..131071
        #pragma unroll
        for (int j = 0; j < 4; ++j) {
            int i = g + j * 131072;
            emao_out[i] = 0.99f * ema_w[i];
        }
    }
    const int b = n >> 10, hw = n & 1023;
    const float* er = emb + idx * 64 + q * 16;
    float4 e0 = *(const float4*)er, e1 = *(const float4*)(er + 4);
    float4 e2 = *(const float4*)(er + 8), e3 = *(const float4*)(er + 12);
    float ev[16] = {e0.x, e0.y, e0.z, e0.w, e1.x, e1.y, e1.z, e1.w,
                    e2.x, e2.y, e2.z, e2.w, e3.x, e3.y, e3.z, e3.w};
    float lsum = 0.f;
    #pragma unroll
    for (int j = 0; j < 16; ++j) {
        int c = q * 16 + j;
        float zv = z[b * CHW + c * HWSZ + hw];
        float dd = ev[j] - zv;
        zq_out[b * CHW + c * HWSZ + hw] = zv + dd;
        if (z_t) z_t[n * 64 + c] = zv;
        lsum += dd * dd;
    }
    #pragma unroll
    for (int m = 32; m >= 1; m >>= 1) lsum += __shfl_xor(lsum, m, 64);
    if ((tid & 63) == 0) atomicAdd(loss_sum, lsum);

    // ---- last-block election ----
    __threadfence();
    __syncthreads();
    if (tid == 0) is_last = (atomicAdd(done_ctr, 1) == (int)gridDim.x - 1);
    __syncthreads();
    if (!is_last) return;
    __threadfence();

    // ---- scan phase (pass 1: per-thread sums over 32 codes) ----
    int part = 0; float fpart = 0.f;
    for (int j = 0; j < 32; ++j) {
        int c = tid * 32 + j;
        int cnt = cnt_i[c];
        part  += cnt;
        fpart += 0.99f * csize[c] + 0.01f * (float)cnt;
    }
    sc[tid]  = part;
    sfr[tid] = fpart;
    __syncthreads();
    for (int off = 1; off < 256; off <<= 1) {
        int add = (tid >= off) ? sc[tid - off] : 0;
        __syncthreads();
        sc[tid] += add;
        __syncthreads();
    }
    for (int off = 128; off >= 1; off >>= 1) {
        if (tid < off) sfr[tid] += sfr[tid + off];
        __syncthreads();
    }
    float denom = sfr[0] + (float)(K_CODES * 1e-5);
    // pass 2: cursor + csn
    int run = sc[tid] - part;
    for (int j = 0; j < 32; ++j) {
        int c = tid * 32 + j;
        int cnt = cnt_i[c];
        float cv = 0.99f * csize[c] + 0.01f * (float)cnt;
        curs[c] = run;
        run += cnt;
        csn_out[c] = (cv + 1e-5f) / denom;
    }
    if (tid == 0) *loss_out = 0.25f * (*loss_sum) * (1.0f / (float)NELEM);
    __syncthreads();

    // ---- scatter phase: 32768 tokens, 128 per thread, LDS cursor ----
    for (int j = 0; j < 128; ++j) {
        int tk = j * 256 + tid;
        int k  = idx_i32[tk];
        int pos = atomicAdd(&curs[k], 1);
        tok_of[pos]  = tk;
        code_of[pos] = k;
    }
}

// ------- ema_fused: ema_acc + grid barrier + distributed final_div -----------
// 128 blocks (<= 256 CUs -> all co-resident, barrier cannot deadlock).
__global__ __launch_bounds__(256) void ema_fused(const float* __restrict__ z,
                                                 const float* __restrict__ z_t,
                                                 const int* __restrict__ tok_of,
                                                 const int* __restrict__ code_of,
                                                 float* __restrict__ emao_out,
                                                 const float* __restrict__ csn_out,
                                                 float* __restrict__ embo_out,
                                                 int* __restrict__ bar) {
    const int wv   = (blockIdx.x * 256 + threadIdx.x) >> 6;   // 0..511
    const int lane = threadIdx.x & 63;
    const int pos0 = wv * 64;
    const int tok  = tok_of[pos0 + lane];
    const int cod  = code_of[pos0 + lane];
    float acc = 0.f;
    #pragma unroll
    for (int g = 0; g < 8; ++g) {
        int tk[8], kk[8];
        #pragma unroll
        for (int j = 0; j < 8; ++j) {
            tk[j] = __shfl(tok, g * 8 + j, 64);
            kk[j] = __shfl(cod, g * 8 + j, 64);
        }
        float v[8];
        if (z_t) {
            #pragma unroll
            for (int j = 0; j < 8; ++j) v[j] = z_t[tk[j] * 64 + lane];
        } else {
            #pragma unroll
            for (int j = 0; j < 8; ++j)
                v[j] = z[(tk[j] >> 10) * CHW + lane * HWSZ + (tk[j] & 1023)];
        }
        int knext = (g < 7) ? __shfl(cod, g * 8 + 8, 64) : -1;
        #pragma unroll
        for (int j = 0; j < 8; ++j) {
            acc += v[j];
            int kn = (j < 7) ? kk[j + 1] : knext;
            if (kn != kk[j]) {
                atomicAdd(&emao_out[kk[j] * 64 + lane], 0.01f * acc);
                acc = 0.f;
            }
        }
    }

    // ---- grid barrier (fence -> block done -> signal -> spin) ----
    __threadfence();
    __syncthreads();
    if (threadIdx.x == 0) {
        atomicAdd(bar, 1);
        while (atomicAdd(bar, 0) < (int)gridDim.x) __builtin_amdgcn_s_sleep(8);
    }
    __syncthreads();
    __threadfence();

    // ---- final_div distributed: 524288 elems / 128 blocks = 4096 each ----
    const int base = blockIdx.x * 4096 + threadIdx.x;
    #pragma unroll
    for (int j = 0; j < 16; ++j) {
        int g = base + j * 256;
        float ev = __hip_atomic_load(&emao_out[g], __ATOMIC_RELAXED,
                                     __HIP_MEMORY_SCOPE_AGENT);
        embo_out[g] = ev / csn_out[g >> 6];
    }
}

extern "C" void kernel_launch(void* const* d_in, const int* in_sizes, int n_in,
                              void* d_out, int out_size, void* d_ws, size_t ws_size,
                              hipStream_t stream) {
    (void)in_sizes; (void)n_in; (void)out_size;
    const float* z     = (const float*)d_in[0];
    const float* emb   = (const float*)d_in[1];
    const float* ema_w = (const float*)d_in[2];
    const float* csize = (const float*)d_in[3];

    float* out      = (float*)d_out;
    float* zq_out   = out;
    float* loss_out = out + 2097152;
    float* idx_out  = out + 2097153;
    float* csn_out  = out + 2129921;
    float* emao_out = out + 2138113;
    float* embo_out = out + 2662401;

    char* wsb = (char*)d_ws;
    unsigned short*     blob    = (unsigned short*)(wsb);              // 2,097,152 B
    float*              eng     = (float*)(wsb + 2097152);             // 32 KB
    unsigned long long* packed  = (unsigned long long*)(wsb + 2129920);// 256 KB
    int*                code_of = (int*)(wsb + 2129920);               // aliases packed (dead after zq body)
    int*                idx_i32 = (int*)(wsb + 2392064);               // 128 KB
    int*                cnt_i   = (int*)(wsb + 2523136);               // 32 KB
    float*              sums    = (float*)(wsb + 2555904);             // 8 B
    int*                ctrs    = (int*)(wsb + 2555920);               // counters (ex-cursor)
    int*                tok_of  = (int*)(wsb + 2588688);               // 128 KB
    const size_t zt_off = 2719760;
    float* z_t = (ws_size >= zt_off + (size_t)NELEM * 4) ? (float*)(wsb + zt_off) : nullptr;

    prep_e<<<128, 256, 0, stream>>>(emb, blob, eng, packed, cnt_i, sums, ctrs);
    vq_argmin<<<1024, 256, 0, stream>>>(z, blob, eng, packed);
    zq_fused<<<N_TOK / 64, 256, 0, stream>>>(z, emb, ema_w, csize, packed, zq_out,
                                             idx_out, idx_i32, cnt_i, sums + 1, z_t,
                                             emao_out, ctrs, tok_of, code_of,
                                             csn_out, loss_out);
    ema_fused<<<128, 256, 0, stream>>>(z, z_t, tok_of, code_of, emao_out,
                                       csn_out, embo_out, ctrs + 1);
}

// Round 8
// 259.980 us; speedup vs baseline: 1.3049x; 1.3049x over previous
//
#include <hip/hip_runtime.h>
#include <float.h>

#define N_TOK   32768
#define DIM     64
#define K_CODES 8192
#define HWSZ    1024
#define CHW     65536
#define NELEM   2097152

typedef short  bf16x8 __attribute__((ext_vector_type(8)));
typedef float  f32x16 __attribute__((ext_vector_type(16)));

static __device__ __forceinline__ unsigned short f2bf(float x) {
    unsigned u = __float_as_uint(x);
    unsigned r = u + 0x7FFFu + ((u >> 16) & 1u);
    return (unsigned short)(r >> 16);
}
static __device__ __forceinline__ float bf2f(unsigned short h) {
    return __uint_as_float(((unsigned)h) << 16);
}

// ------- prep_e: emb -> frag-ordered bf16 hi/lo blob + ||e||^2 + ws zeroing --
__global__ __launch_bounds__(256) void prep_e(const float* __restrict__ emb,
                                              unsigned short* __restrict__ blob,
                                              float* __restrict__ eng,
                                              unsigned long long* __restrict__ packed,
                                              int* __restrict__ cnt_i,
                                              float* __restrict__ sums) {
    __shared__ float part[512];
    const int gid = blockIdx.x * 256 + threadIdx.x;   // 0..32767
    packed[gid] = ~0ull;                              // init for atomicMin
    if (gid < K_CODES) cnt_i[gid] = 0;
    if (gid < 2) sums[gid] = 0.f;

    int tile = blockIdx.x;
    #pragma unroll
    for (int u0 = 0; u0 < 2; ++u0) {
        int u = threadIdx.x + u0 * 256;
        int s = u >> 7, h = (u >> 6) & 1, n = u & 63;
        const float* src = emb + (tile * 64 + n) * 64 + s * 16 + h * 8;
        float4 v0 = *(const float4*)src;
        float4 v1 = *(const float4*)(src + 4);
        float x[8] = {v0.x, v0.y, v0.z, v0.w, v1.x, v1.y, v1.z, v1.w};
        unsigned short hi[8], lo[8];
        float ss = 0.f;
        #pragma unroll
        for (int j = 0; j < 8; ++j) {
            hi[j] = f2bf(x[j]);
            lo[j] = f2bf(x[j] - bf2f(hi[j]));
            ss += x[j] * x[j];
        }
        part[u] = ss;
        unsigned short* dhi = blob + (size_t)tile * 8192 + ((s * 2 + 0) * 2 + h) * 512 + n * 8;
        unsigned short* dlo = blob + (size_t)tile * 8192 + ((s * 2 + 1) * 2 + h) * 512 + n * 8;
        uint4 ph, pl;
        ph.x = (unsigned)hi[0] | ((unsigned)hi[1] << 16);
        ph.y = (unsigned)hi[2] | ((unsigned)hi[3] << 16);
        ph.z = (unsigned)hi[4] | ((unsigned)hi[5] << 16);
        ph.w = (unsigned)hi[6] | ((unsigned)hi[7] << 16);
        pl.x = (unsigned)lo[0] | ((unsigned)lo[1] << 16);
        pl.y = (unsigned)lo[2] | ((unsigned)lo[3] << 16);
        pl.z = (unsigned)lo[4] | ((unsigned)lo[5] << 16);
        pl.w = (unsigned)lo[6] | ((unsigned)lo[7] << 16);
        *(uint4*)dhi = ph;
        *(uint4*)dlo = pl;
    }
    __syncthreads();
    if (threadIdx.x < 64) {
        float s = 0.f;
        #pragma unroll
        for (int j = 0; j < 8; ++j) s += part[threadIdx.x + j * 64];
        eng[tile * 64 + threadIdx.x] = s;
    }
}

// ---------------- argmin: software-pipelined, eng-seeded acc (R4 exact) ------
__global__ __launch_bounds__(256, 3) void vq_argmin(const float* __restrict__ z,
                                                    const unsigned short* __restrict__ blob,
                                                    const float* __restrict__ eng,
                                                    unsigned long long* __restrict__ packed) {
    __shared__ __align__(16) unsigned short zh[64 * 72];
    __shared__ __align__(16) unsigned short zl[64 * 72];
    __shared__ unsigned long long red[64 * 4];

    const int tid  = threadIdx.x;
    const int lane = tid & 63;
    const int wid  = tid >> 6;           // 0..3
    const int l31  = lane & 31, h = lane >> 5;

    const int tb = blockIdx.x & 511;     // token-tile id 0..511
    const int ks = blockIdx.x >> 9;      // K split 0/1
    const int n0 = tb * 64;
    const int zbase = (n0 >> 10) * CHW + (n0 & 1023);

    // ---- stage -2*z as bf16 hi/lo (64 tokens x 64 dims) ----
    {
        int f4 = tid & 15;               // 16 float4 = 64 tokens per channel
        int c0 = tid >> 4;               // 0..15
        #pragma unroll
        for (int r = 0; r < 4; ++r) {
            int c = c0 * 4 + r;
            float4 v = *(const float4*)(z + zbase + c * HWSZ + f4 * 4);
            float x[4] = {v.x, v.y, v.z, v.w};
            #pragma unroll
            for (int e = 0; e < 4; ++e) {
                int t = f4 * 4 + e;
                float xs = -2.0f * x[e];
                unsigned short hi = f2bf(xs);
                zh[t * 72 + c] = hi;
                zl[t * 72 + c] = f2bf(xs - bf2f(hi));
            }
        }
    }
    __syncthreads();

    // ---- resident token fragments (B operand), both 32-token tiles ----
    bf16x8 T0h[4], T0l[4], T1h[4], T1l[4];
    {
        int r0 = l31;        // tile 0 token
        int r1 = 32 + l31;   // tile 1 token
        #pragma unroll
        for (int s = 0; s < 4; ++s) {
            T0h[s] = *(const bf16x8*)(&zh[r0 * 72 + s * 16 + h * 8]);
            T0l[s] = *(const bf16x8*)(&zl[r0 * 72 + s * 16 + h * 8]);
            T1h[s] = *(const bf16x8*)(&zh[r1 * 72 + s * 16 + h * 8]);
            T1l[s] = *(const bf16x8*)(&zl[r1 * 72 + s * 16 + h * 8]);
        }
    }

    const int hk0 = ks * 128 + wid;
    const unsigned short* bp = blob + (size_t)(hk0 >> 1) * 8192 + ((hk0 & 1) * 32 + l31) * 8;
    const float* ep = eng + (hk0 >> 1) * 64 + (hk0 & 1) * 32 + 4 * h;
    int scode = __builtin_amdgcn_readfirstlane((hk0 >> 1) * 64 + (hk0 & 1) * 32);

    // prologue: first tile's E frags + eng
    bf16x8 Eh[4], El[4];
    #pragma unroll
    for (int s = 0; s < 4; ++s) {
        Eh[s] = *(const bf16x8*)(bp + (4 * s + h) * 512);
        El[s] = *(const bf16x8*)(bp + (4 * s + 2 + h) * 512);
    }
    float4 g0 = *(const float4*)(ep);
    float4 g1 = *(const float4*)(ep + 8);
    float4 g2 = *(const float4*)(ep + 16);
    float4 g3 = *(const float4*)(ep + 24);

    float minv0 = FLT_MAX, minv1 = FLT_MAX;
    int   mini0 = 0,       mini1 = 0;

    for (int i = 0; i < 32; ++i) {
        // seed acc with ||e||^2 (round-2 numerics: eng is the MFMA C operand)
        f32x16 ac0, ac1;
        ac0[0]  = g0.x; ac0[1]  = g0.y; ac0[2]  = g0.z; ac0[3]  = g0.w;
        ac0[4]  = g1.x; ac0[5]  = g1.y; ac0[6]  = g1.z; ac0[7]  = g1.w;
        ac0[8]  = g2.x; ac0[9]  = g2.y; ac0[10] = g2.z; ac0[11] = g2.w;
        ac0[12] = g3.x; ac0[13] = g3.y; ac0[14] = g3.z; ac0[15] = g3.w;
        ac1 = ac0;

        // prefetch next tile's eng (g regs dead after seed)
        ep += 128;
        g0 = *(const float4*)(ep);
        g1 = *(const float4*)(ep + 8);
        g2 = *(const float4*)(ep + 16);
        g3 = *(const float4*)(ep + 24);

        __builtin_amdgcn_s_setprio(1);
        #pragma unroll
        for (int s = 0; s < 4; ++s) {
            ac0 = __builtin_amdgcn_mfma_f32_32x32x16_bf16(El[s], T0h[s], ac0, 0, 0, 0);
            ac1 = __builtin_amdgcn_mfma_f32_32x32x16_bf16(El[s], T1h[s], ac1, 0, 0, 0);
            ac0 = __builtin_amdgcn_mfma_f32_32x32x16_bf16(Eh[s], T0l[s], ac0, 0, 0, 0);
            ac1 = __builtin_amdgcn_mfma_f32_32x32x16_bf16(Eh[s], T1l[s], ac1, 0, 0, 0);
            ac0 = __builtin_amdgcn_mfma_f32_32x32x16_bf16(Eh[s], T0h[s], ac0, 0, 0, 0);
            ac1 = __builtin_amdgcn_mfma_f32_32x32x16_bf16(Eh[s], T1h[s], ac1, 0, 0, 0);
        }
        __builtin_amdgcn_s_setprio(0);

        // prefetch next tile's E frags (E regs dead once MFMAs issued)
        bp += 2 * 8192;   // hk += 4  ->  2 kt tiles of 8192 shorts
        #pragma unroll
        for (int s = 0; s < 4; ++s) {
            Eh[s] = *(const bf16x8*)(bp + (4 * s + h) * 512);
            El[s] = *(const bf16x8*)(bp + (4 * s + 2 + h) * 512);
        }

        // epilogue: acc IS the distance; min-update (cmp + 2 sel)
        #pragma unroll
        for (int r = 0; r < 16; ++r) {
            int code = scode + ((r & 3) + 8 * (r >> 2));
            if (ac0[r] < minv0) { minv0 = ac0[r]; mini0 = code; }
            if (ac1[r] < minv1) { minv1 = ac1[r]; mini1 = code; }
        }
        scode += 128;
    }
    mini0 += 4 * h;   // lane-dependent part of code, applied once
    mini1 += 4 * h;

    // ---- merge h halves (same token, disjoint code rows), then waves ----
    unsigned u0 = __float_as_uint(minv0);
    u0 = (u0 & 0x80000000u) ? ~u0 : (u0 | 0x80000000u);
    unsigned long long k0 = ((unsigned long long)u0 << 32) | (unsigned)mini0;
    unsigned u1 = __float_as_uint(minv1);
    u1 = (u1 & 0x80000000u) ? ~u1 : (u1 | 0x80000000u);
    unsigned long long k1 = ((unsigned long long)u1 << 32) | (unsigned)mini1;
    unsigned long long o0 = __shfl_xor(k0, 32, 64);
    if (o0 < k0) k0 = o0;
    unsigned long long o1 = __shfl_xor(k1, 32, 64);
    if (o1 < k1) k1 = o1;
    if (h == 0) {
        red[l31 * 4 + wid]        = k0;
        red[(32 + l31) * 4 + wid] = k1;
    }
    __syncthreads();
    if (tid < 64) {
        unsigned long long a = red[tid * 4], b = red[tid * 4 + 1];
        unsigned long long c = red[tid * 4 + 2], d = red[tid * 4 + 3];
        unsigned long long m = (b < a) ? b : a;
        if (c < m) m = c;
        if (d < m) m = d;
        atomicMin(&packed[n0 + tid], m);
    }
}

// ------- zq_loss v2: LDS-staged, fully coalesced global traffic --------------
// Per block: 64 tokens. Gather emb rows + z tile into LDS, then emit:
//   z read      channel-major float4 (256B/instr)
//   z_t write   token-major  float4
//   zq_out write channel-major float4 (was 4KB-strided scalars -> 1.6x write
//                inflation, 250 GB/s in R7's counters)
// Per-element arithmetic, per-thread loss order, and wave reduction are
// identical ops in identical order to R4 -> bit-exact outputs.
__global__ __launch_bounds__(256) void zq_loss(const float* __restrict__ z,
                                               const float* __restrict__ emb,
                                               const float* __restrict__ ema_w,
                                               const unsigned long long* __restrict__ packed,
                                               float* __restrict__ zq_out,
                                               float* __restrict__ idx_out,
                                               int* __restrict__ idx_i32,
                                               int* __restrict__ cnt_i,
                                               float* __restrict__ loss_sum,
                                               float* __restrict__ z_t,
                                               float* __restrict__ emao_out) {
    __shared__ float e_lds[64][68];
    __shared__ float z_lds[64][68];

    const int tid = threadIdx.x;
    const int n0  = blockIdx.x * 64;
    const int t   = tid >> 2, q = tid & 3;
    const int n   = n0 + t;
    const int b   = n0 >> 10;            // whole block shares b
    const int hw0 = n0 & 1023;
    const int zb  = b * CHW + hw0;

    const int idx = (int)(packed[n] & 0xFFFFFFFFull);
    if (q == 0) {
        idx_out[n] = (float)idx;
        idx_i32[n] = idx;
        atomicAdd(&cnt_i[idx], 1);
    }
    // emao init: 4 strided elements per thread, coalesced scalar stores
    {
        int g = blockIdx.x * 256 + tid;         // 0..131071
        #pragma unroll
        for (int j = 0; j < 4; ++j) {
            int i = g + j * 131072;
            emao_out[i] = 0.99f * ema_w[i];
        }
    }
    // gather emb row -> e_lds[t][q*16..]
    {
        const float* er = emb + idx * 64 + q * 16;
        float4 e0 = *(const float4*)er,       e1 = *(const float4*)(er + 4);
        float4 e2 = *(const float4*)(er + 8), e3 = *(const float4*)(er + 12);
        *(float4*)&e_lds[t][q * 16]      = e0;
        *(float4*)&e_lds[t][q * 16 + 4]  = e1;
        *(float4*)&e_lds[t][q * 16 + 8]  = e2;
        *(float4*)&e_lds[t][q * 16 + 12] = e3;
    }
    // stage z channel-major (coalesced) -> z_lds[token][c]
    {
        const int f4 = tid & 15, c0 = tid >> 4;
        #pragma unroll
        for (int r = 0; r < 4; ++r) {
            int c = c0 * 4 + r;
            float4 v = *(const float4*)(z + zb + c * HWSZ + f4 * 4);
            z_lds[f4 * 4 + 0][c] = v.x;
            z_lds[f4 * 4 + 1][c] = v.y;
            z_lds[f4 * 4 + 2][c] = v.z;
            z_lds[f4 * 4 + 3][c] = v.w;
        }
    }
    __syncthreads();

    // z_t write: token-major, fully coalesced
    if (z_t) {
        #pragma unroll
        for (int u = 0; u < 4; ++u)
            *(float4*)&z_t[n * 64 + q * 16 + u * 4] = *(float4*)&z_lds[t][q * 16 + u * 4];
    }
    // zq_out write: channel-major, fully coalesced; same per-element arithmetic
    {
        const int f4 = tid & 15, c0 = tid >> 4;
        #pragma unroll
        for (int r = 0; r < 4; ++r) {
            int c = c0 * 4 + r;
            float4 o;
            { float zv = z_lds[f4*4+0][c]; o.x = zv + (e_lds[f4*4+0][c] - zv); }
            { float zv = z_lds[f4*4+1][c]; o.y = zv + (e_lds[f4*4+1][c] - zv); }
            { float zv = z_lds[f4*4+2][c]; o.z = zv + (e_lds[f4*4+2][c] - zv); }
            { float zv = z_lds[f4*4+3][c]; o.w = zv + (e_lds[f4*4+3][c] - zv); }
            *(float4*)(zq_out + zb + c * HWSZ + f4 * 4) = o;
        }
    }
    // loss: per-thread order identical to R4 (c = q*16+j ascending)
    float lsum = 0.f;
    #pragma unroll
    for (int j = 0; j < 16; ++j) {
        int c = q * 16 + j;
        float dd = e_lds[t][c] - z_lds[t][c];
        lsum += dd * dd;
    }
    #pragma unroll
    for (int m = 32; m >= 1; m >>= 1) lsum += __shfl_xor(lsum, m, 64);
    if ((tid & 63) == 0) atomicAdd(loss_sum, lsum);
}

// ------- scan_scatter: R4 scan_cs + in-block scatter via LDS cursor ----------
// Single 1024-thread block. Scan numerics identical to R4's scan_cs; the
// scatter (previously a separate kernel + global cursor) runs in the same
// block off a 32KB LDS cursor holding the same exclusive-prefix values.
__global__ __launch_bounds__(1024) void scan_scatter(const int* __restrict__ cnt_i,
                                                     const float* __restrict__ csize,
                                                     const float* __restrict__ loss_sum,
                                                     const int* __restrict__ idx_i32,
                                                     int* __restrict__ tok_of,
                                                     int* __restrict__ code_of,
                                                     float* __restrict__ csn_out,
                                                     float* __restrict__ loss_out) {
    __shared__ int   sc[1024];
    __shared__ float sf[1024];
    __shared__ int   curs[8192];
    const int tid = threadIdx.x;
    int v[8], part = 0;
    float cv[8], fpart = 0.f;
    #pragma unroll
    for (int j = 0; j < 8; ++j) { v[j] = cnt_i[tid * 8 + j]; part += v[j]; }
    #pragma unroll
    for (int j = 0; j < 8; ++j) {
        cv[j] = 0.99f * csize[tid * 8 + j] + 0.01f * (float)v[j];
        fpart += cv[j];
    }
    sc[tid] = part;
    sf[tid] = fpart;
    __syncthreads();
    for (int off = 1; off < 1024; off <<= 1) {
        int add = (tid >= off) ? sc[tid - off] : 0;
        __syncthreads();
        sc[tid] += add;
        __syncthreads();
    }
    int run = sc[tid] - part;
    #pragma unroll
    for (int j = 0; j < 8; ++j) {
        curs[tid * 8 + j] = run;
        run += v[j];
    }
    for (int off = 512; off >= 1; off >>= 1) {
        if (tid < off) sf[tid] += sf[tid + off];
        __syncthreads();
    }
    float denom = sf[0] + (float)(K_CODES * 1e-5);
    #pragma unroll
    for (int j = 0; j < 8; ++j) csn_out[tid * 8 + j] = (cv[j] + 1e-5f) / denom;
    if (tid == 0) *loss_out = 0.25f * (*loss_sum) * (1.0f / (float)NELEM);
    __syncthreads();

    // scatter: 32768 tokens, 32 per thread, LDS-cursor atomics
    for (int j = 0; j < 32; ++j) {
        int tk = j * 1024 + tid;
        int k  = idx_i32[tk];
        int pos = atomicAdd(&curs[k], 1);
        tok_of[pos]  = tk;
        code_of[pos] = k;
    }
}

// ------- ema_acc: balanced 64-position chunks, pipelined loads ---------------
__global__ __launch_bounds__(256) void ema_acc(const float* __restrict__ z,
                                               const float* __restrict__ z_t,
                                               const int* __restrict__ tok_of,
                                               const int* __restrict__ code_of,
                                               float* __restrict__ emao_out) {
    const int wv   = (blockIdx.x * 256 + threadIdx.x) >> 6;   // 0..511
    const int lane = threadIdx.x & 63;
    const int pos0 = wv * 64;
    const int tok  = tok_of[pos0 + lane];
    const int cod  = code_of[pos0 + lane];
    float acc = 0.f;
    #pragma unroll
    for (int g = 0; g < 8; ++g) {
        int tk[8], kk[8];
        #pragma unroll
        for (int j = 0; j < 8; ++j) {
            tk[j] = __shfl(tok, g * 8 + j, 64);
            kk[j] = __shfl(cod, g * 8 + j, 64);
        }
        float v[8];
        if (z_t) {
            #pragma unroll
            for (int j = 0; j < 8; ++j) v[j] = z_t[tk[j] * 64 + lane];
        } else {
            #pragma unroll
            for (int j = 0; j < 8; ++j)
                v[j] = z[(tk[j] >> 10) * CHW + lane * HWSZ + (tk[j] & 1023)];
        }
        int knext = (g < 7) ? __shfl(cod, g * 8 + 8, 64) : -1;
        #pragma unroll
        for (int j = 0; j < 8; ++j) {
            acc += v[j];
            int kn = (j < 7) ? kk[j + 1] : knext;
            if (kn != kk[j]) {
                atomicAdd(&emao_out[kk[j] * 64 + lane], 0.01f * acc);
                acc = 0.f;
            }
        }
    }
}

// ------- final_div: emb_out = emao / csn -------------------------------------
__global__ __launch_bounds__(256) void final_div(const float* __restrict__ emao_out,
                                                 const float* __restrict__ csn_out,
                                                 float* __restrict__ embo_out) {
    int g = blockIdx.x * 256 + threadIdx.x;
    embo_out[g] = emao_out[g] / csn_out[g >> 6];
}

extern "C" void kernel_launch(void* const* d_in, const int* in_sizes, int n_in,
                              void* d_out, int out_size, void* d_ws, size_t ws_size,
                              hipStream_t stream) {
    (void)in_sizes; (void)n_in; (void)out_size;
    const float* z     = (const float*)d_in[0];
    const float* emb   = (const float*)d_in[1];
    const float* ema_w = (const float*)d_in[2];
    const float* csize = (const float*)d_in[3];

    float* out      = (float*)d_out;
    float* zq_out   = out;
    float* loss_out = out + 2097152;
    float* idx_out  = out + 2097153;
    float* csn_out  = out + 2129921;
    float* emao_out = out + 2138113;
    float* embo_out = out + 2662401;

    char* wsb = (char*)d_ws;
    unsigned short*     blob    = (unsigned short*)(wsb);              // 2,097,152 B
    float*              eng     = (float*)(wsb + 2097152);             // 32 KB
    unsigned long long* packed  = (unsigned long long*)(wsb + 2129920);// 256 KB
    int*                code_of = (int*)(wsb + 2129920);               // aliases packed (dead after zq_loss)
    int*                idx_i32 = (int*)(wsb + 2392064);               // 128 KB
    int*                cnt_i   = (int*)(wsb + 2523136);               // 32 KB
    float*              sums    = (float*)(wsb + 2555904);             // 8 B
    int*                tok_of  = (int*)(wsb + 2588688);               // 128 KB
    const size_t zt_off = 2719760;
    float* z_t = (ws_size >= zt_off + (size_t)NELEM * 4) ? (float*)(wsb + zt_off) : nullptr;

    prep_e<<<128, 256, 0, stream>>>(emb, blob, eng, packed, cnt_i, sums);
    vq_argmin<<<1024, 256, 0, stream>>>(z, blob, eng, packed);
    zq_loss<<<N_TOK / 64, 256, 0, stream>>>(z, emb, ema_w, packed, zq_out, idx_out,
                                            idx_i32, cnt_i, sums + 1, z_t, emao_out);
    scan_scatter<<<1, 1024, 0, stream>>>(cnt_i, csize, sums + 1, idx_i32,
                                         tok_of, code_of, csn_out, loss_out);
    ema_acc<<<128, 256, 0, stream>>>(z, z_t, tok_of, code_of, emao_out);
    final_div<<<K_CODES * DIM / 256, 256, 0, stream>>>(emao_out, csn_out, embo_out);
}

// Round 9
// 216.455 us; speedup vs baseline: 1.5673x; 1.2011x over previous
//
#include <hip/hip_runtime.h>
#include <float.h>

#define N_TOK   32768
#define DIM     64
#define K_CODES 8192
#define HWSZ    1024
#define CHW     65536
#define NELEM   2097152

typedef short  bf16x8 __attribute__((ext_vector_type(8)));
typedef float  f32x16 __attribute__((ext_vector_type(16)));

static __device__ __forceinline__ unsigned short f2bf(float x) {
    unsigned u = __float_as_uint(x);
    unsigned r = u + 0x7FFFu + ((u >> 16) & 1u);
    return (unsigned short)(r >> 16);
}
static __device__ __forceinline__ float bf2f(unsigned short h) {
    return __uint_as_float(((unsigned)h) << 16);
}

// ------- prep_e: emb -> frag-ordered bf16 hi/lo blob + ||e||^2 + ws zeroing --
__global__ __launch_bounds__(256) void prep_e(const float* __restrict__ emb,
                                              unsigned short* __restrict__ blob,
                                              float* __restrict__ eng,
                                              unsigned long long* __restrict__ packed,
                                              int* __restrict__ cnt_i,
                                              float* __restrict__ sums) {
    __shared__ float part[512];
    const int gid = blockIdx.x * 256 + threadIdx.x;   // 0..32767
    packed[gid] = ~0ull;                              // init for atomicMin
    if (gid < K_CODES) cnt_i[gid] = 0;
    if (gid < 2) sums[gid] = 0.f;

    int tile = blockIdx.x;
    #pragma unroll
    for (int u0 = 0; u0 < 2; ++u0) {
        int u = threadIdx.x + u0 * 256;
        int s = u >> 7, h = (u >> 6) & 1, n = u & 63;
        const float* src = emb + (tile * 64 + n) * 64 + s * 16 + h * 8;
        float4 v0 = *(const float4*)src;
        float4 v1 = *(const float4*)(src + 4);
        float x[8] = {v0.x, v0.y, v0.z, v0.w, v1.x, v1.y, v1.z, v1.w};
        unsigned short hi[8], lo[8];
        float ss = 0.f;
        #pragma unroll
        for (int j = 0; j < 8; ++j) {
            hi[j] = f2bf(x[j]);
            lo[j] = f2bf(x[j] - bf2f(hi[j]));
            ss += x[j] * x[j];
        }
        part[u] = ss;
        unsigned short* dhi = blob + (size_t)tile * 8192 + ((s * 2 + 0) * 2 + h) * 512 + n * 8;
        unsigned short* dlo = blob + (size_t)tile * 8192 + ((s * 2 + 1) * 2 + h) * 512 + n * 8;
        uint4 ph, pl;
        ph.x = (unsigned)hi[0] | ((unsigned)hi[1] << 16);
        ph.y = (unsigned)hi[2] | ((unsigned)hi[3] << 16);
        ph.z = (unsigned)hi[4] | ((unsigned)hi[5] << 16);
        ph.w = (unsigned)hi[6] | ((unsigned)hi[7] << 16);
        pl.x = (unsigned)lo[0] | ((unsigned)lo[1] << 16);
        pl.y = (unsigned)lo[2] | ((unsigned)lo[3] << 16);
        pl.z = (unsigned)lo[4] | ((unsigned)lo[5] << 16);
        pl.w = (unsigned)lo[6] | ((unsigned)lo[7] << 16);
        *(uint4*)dhi = ph;
        *(uint4*)dlo = pl;
    }
    __syncthreads();
    if (threadIdx.x < 64) {
        float s = 0.f;
        #pragma unroll
        for (int j = 0; j < 8; ++j) s += part[threadIdx.x + j * 64];
        eng[tile * 64 + threadIdx.x] = s;
    }
}

// ---------------- argmin: software-pipelined, eng-seeded acc (R4 exact) ------
__global__ __launch_bounds__(256, 3) void vq_argmin(const float* __restrict__ z,
                                                    const unsigned short* __restrict__ blob,
                                                    const float* __restrict__ eng,
                                                    unsigned long long* __restrict__ packed) {
    __shared__ __align__(16) unsigned short zh[64 * 72];
    __shared__ __align__(16) unsigned short zl[64 * 72];
    __shared__ unsigned long long red[64 * 4];

    const int tid  = threadIdx.x;
    const int lane = tid & 63;
    const int wid  = tid >> 6;           // 0..3
    const int l31  = lane & 31, h = lane >> 5;

    const int tb = blockIdx.x & 511;     // token-tile id 0..511
    const int ks = blockIdx.x >> 9;      // K split 0/1
    const int n0 = tb * 64;
    const int zbase = (n0 >> 10) * CHW + (n0 & 1023);

    // ---- stage -2*z as bf16 hi/lo (64 tokens x 64 dims) ----
    {
        int f4 = tid & 15;               // 16 float4 = 64 tokens per channel
        int c0 = tid >> 4;               // 0..15
        #pragma unroll
        for (int r = 0; r < 4; ++r) {
            int c = c0 * 4 + r;
            float4 v = *(const float4*)(z + zbase + c * HWSZ + f4 * 4);
            float x[4] = {v.x, v.y, v.z, v.w};
            #pragma unroll
            for (int e = 0; e < 4; ++e) {
                int t = f4 * 4 + e;
                float xs = -2.0f * x[e];
                unsigned short hi = f2bf(xs);
                zh[t * 72 + c] = hi;
                zl[t * 72 + c] = f2bf(xs - bf2f(hi));
            }
        }
    }
    __syncthreads();

    // ---- resident token fragments (B operand), both 32-token tiles ----
    bf16x8 T0h[4], T0l[4], T1h[4], T1l[4];
    {
        int r0 = l31;        // tile 0 token
        int r1 = 32 + l31;   // tile 1 token
        #pragma unroll
        for (int s = 0; s < 4; ++s) {
            T0h[s] = *(const bf16x8*)(&zh[r0 * 72 + s * 16 + h * 8]);
            T0l[s] = *(const bf16x8*)(&zl[r0 * 72 + s * 16 + h * 8]);
            T1h[s] = *(const bf16x8*)(&zh[r1 * 72 + s * 16 + h * 8]);
            T1l[s] = *(const bf16x8*)(&zl[r1 * 72 + s * 16 + h * 8]);
        }
    }

    const int hk0 = ks * 128 + wid;
    const unsigned short* bp = blob + (size_t)(hk0 >> 1) * 8192 + ((hk0 & 1) * 32 + l31) * 8;
    const float* ep = eng + (hk0 >> 1) * 64 + (hk0 & 1) * 32 + 4 * h;
    int scode = __builtin_amdgcn_readfirstlane((hk0 >> 1) * 64 + (hk0 & 1) * 32);

    // prologue: first tile's E frags + eng
    bf16x8 Eh[4], El[4];
    #pragma unroll
    for (int s = 0; s < 4; ++s) {
        Eh[s] = *(const bf16x8*)(bp + (4 * s + h) * 512);
        El[s] = *(const bf16x8*)(bp + (4 * s + 2 + h) * 512);
    }
    float4 g0 = *(const float4*)(ep);
    float4 g1 = *(const float4*)(ep + 8);
    float4 g2 = *(const float4*)(ep + 16);
    float4 g3 = *(const float4*)(ep + 24);

    float minv0 = FLT_MAX, minv1 = FLT_MAX;
    int   mini0 = 0,       mini1 = 0;

    for (int i = 0; i < 32; ++i) {
        // seed acc with ||e||^2 (round-2 numerics: eng is the MFMA C operand)
        f32x16 ac0, ac1;
        ac0[0]  = g0.x; ac0[1]  = g0.y; ac0[2]  = g0.z; ac0[3]  = g0.w;
        ac0[4]  = g1.x; ac0[5]  = g1.y; ac0[6]  = g1.z; ac0[7]  = g1.w;
        ac0[8]  = g2.x; ac0[9]  = g2.y; ac0[10] = g2.z; ac0[11] = g2.w;
        ac0[12] = g3.x; ac0[13] = g3.y; ac0[14] = g3.z; ac0[15] = g3.w;
        ac1 = ac0;

        // prefetch next tile's eng (g regs dead after seed)
        ep += 128;
        g0 = *(const float4*)(ep);
        g1 = *(const float4*)(ep + 8);
        g2 = *(const float4*)(ep + 16);
        g3 = *(const float4*)(ep + 24);

        __builtin_amdgcn_s_setprio(1);
        #pragma unroll
        for (int s = 0; s < 4; ++s) {
            ac0 = __builtin_amdgcn_mfma_f32_32x32x16_bf16(El[s], T0h[s], ac0, 0, 0, 0);
            ac1 = __builtin_amdgcn_mfma_f32_32x32x16_bf16(El[s], T1h[s], ac1, 0, 0, 0);
            ac0 = __builtin_amdgcn_mfma_f32_32x32x16_bf16(Eh[s], T0l[s], ac0, 0, 0, 0);
            ac1 = __builtin_amdgcn_mfma_f32_32x32x16_bf16(Eh[s], T1l[s], ac1, 0, 0, 0);
            ac0 = __builtin_amdgcn_mfma_f32_32x32x16_bf16(Eh[s], T0h[s], ac0, 0, 0, 0);
            ac1 = __builtin_amdgcn_mfma_f32_32x32x16_bf16(Eh[s], T1h[s], ac1, 0, 0, 0);
        }
        __builtin_amdgcn_s_setprio(0);

        // prefetch next tile's E frags (E regs dead once MFMAs issued)
        bp += 2 * 8192;   // hk += 4  ->  2 kt tiles of 8192 shorts
        #pragma unroll
        for (int s = 0; s < 4; ++s) {
            Eh[s] = *(const bf16x8*)(bp + (4 * s + h) * 512);
            El[s] = *(const bf16x8*)(bp + (4 * s + 2 + h) * 512);
        }

        // epilogue: acc IS the distance; min-update (cmp + 2 sel)
        #pragma unroll
        for (int r = 0; r < 16; ++r) {
            int code = scode + ((r & 3) + 8 * (r >> 2));
            if (ac0[r] < minv0) { minv0 = ac0[r]; mini0 = code; }
            if (ac1[r] < minv1) { minv1 = ac1[r]; mini1 = code; }
        }
        scode += 128;
    }
    mini0 += 4 * h;   // lane-dependent part of code, applied once
    mini1 += 4 * h;

    // ---- merge h halves (same token, disjoint code rows), then waves ----
    unsigned u0 = __float_as_uint(minv0);
    u0 = (u0 & 0x80000000u) ? ~u0 : (u0 | 0x80000000u);
    unsigned long long k0 = ((unsigned long long)u0 << 32) | (unsigned)mini0;
    unsigned u1 = __float_as_uint(minv1);
    u1 = (u1 & 0x80000000u) ? ~u1 : (u1 | 0x80000000u);
    unsigned long long k1 = ((unsigned long long)u1 << 32) | (unsigned)mini1;
    unsigned long long o0 = __shfl_xor(k0, 32, 64);
    if (o0 < k0) k0 = o0;
    unsigned long long o1 = __shfl_xor(k1, 32, 64);
    if (o1 < k1) k1 = o1;
    if (h == 0) {
        red[l31 * 4 + wid]        = k0;
        red[(32 + l31) * 4 + wid] = k1;
    }
    __syncthreads();
    if (tid < 64) {
        unsigned long long a = red[tid * 4], b = red[tid * 4 + 1];
        unsigned long long c = red[tid * 4 + 2], d = red[tid * 4 + 3];
        unsigned long long m = (b < a) ? b : a;
        if (c < m) m = c;
        if (d < m) m = d;
        atomicMin(&packed[n0 + tid], m);
    }
}

// ------- zq_loss v2: LDS-staged, fully coalesced global traffic --------------
// (validated bit-exact in R8: absmax 2048, passed)
__global__ __launch_bounds__(256) void zq_loss(const float* __restrict__ z,
                                               const float* __restrict__ emb,
                                               const float* __restrict__ ema_w,
                                               const unsigned long long* __restrict__ packed,
                                               float* __restrict__ zq_out,
                                               float* __restrict__ idx_out,
                                               int* __restrict__ idx_i32,
                                               int* __restrict__ cnt_i,
                                               float* __restrict__ loss_sum,
                                               float* __restrict__ z_t,
                                               float* __restrict__ emao_out) {
    __shared__ float e_lds[64][68];
    __shared__ float z_lds[64][68];

    const int tid = threadIdx.x;
    const int n0  = blockIdx.x * 64;
    const int t   = tid >> 2, q = tid & 3;
    const int n   = n0 + t;
    const int b   = n0 >> 10;            // whole block shares b
    const int hw0 = n0 & 1023;
    const int zb  = b * CHW + hw0;

    const int idx = (int)(packed[n] & 0xFFFFFFFFull);
    if (q == 0) {
        idx_out[n] = (float)idx;
        idx_i32[n] = idx;
        atomicAdd(&cnt_i[idx], 1);
    }
    // emao init: 4 strided elements per thread, coalesced scalar stores
    {
        int g = blockIdx.x * 256 + tid;         // 0..131071
        #pragma unroll
        for (int j = 0; j < 4; ++j) {
            int i = g + j * 131072;
            emao_out[i] = 0.99f * ema_w[i];
        }
    }
    // gather emb row -> e_lds[t][q*16..]
    {
        const float* er = emb + idx * 64 + q * 16;
        float4 e0 = *(const float4*)er,       e1 = *(const float4*)(er + 4);
        float4 e2 = *(const float4*)(er + 8), e3 = *(const float4*)(er + 12);
        *(float4*)&e_lds[t][q * 16]      = e0;
        *(float4*)&e_lds[t][q * 16 + 4]  = e1;
        *(float4*)&e_lds[t][q * 16 + 8]  = e2;
        *(float4*)&e_lds[t][q * 16 + 12] = e3;
    }
    // stage z channel-major (coalesced) -> z_lds[token][c]
    {
        const int f4 = tid & 15, c0 = tid >> 4;
        #pragma unroll
        for (int r = 0; r < 4; ++r) {
            int c = c0 * 4 + r;
            float4 v = *(const float4*)(z + zb + c * HWSZ + f4 * 4);
            z_lds[f4 * 4 + 0][c] = v.x;
            z_lds[f4 * 4 + 1][c] = v.y;
            z_lds[f4 * 4 + 2][c] = v.z;
            z_lds[f4 * 4 + 3][c] = v.w;
        }
    }
    __syncthreads();

    // z_t write: token-major, fully coalesced
    if (z_t) {
        #pragma unroll
        for (int u = 0; u < 4; ++u)
            *(float4*)&z_t[n * 64 + q * 16 + u * 4] = *(float4*)&z_lds[t][q * 16 + u * 4];
    }
    // zq_out write: channel-major, fully coalesced; same per-element arithmetic
    {
        const int f4 = tid & 15, c0 = tid >> 4;
        #pragma unroll
        for (int r = 0; r < 4; ++r) {
            int c = c0 * 4 + r;
            float4 o;
            { float zv = z_lds[f4*4+0][c]; o.x = zv + (e_lds[f4*4+0][c] - zv); }
            { float zv = z_lds[f4*4+1][c]; o.y = zv + (e_lds[f4*4+1][c] - zv); }
            { float zv = z_lds[f4*4+2][c]; o.z = zv + (e_lds[f4*4+2][c] - zv); }
            { float zv = z_lds[f4*4+3][c]; o.w = zv + (e_lds[f4*4+3][c] - zv); }
            *(float4*)(zq_out + zb + c * HWSZ + f4 * 4) = o;
        }
    }
    // loss: per-thread order identical to R4 (c = q*16+j ascending)
    float lsum = 0.f;
    #pragma unroll
    for (int j = 0; j < 16; ++j) {
        int c = q * 16 + j;
        float dd = e_lds[t][c] - z_lds[t][c];
        lsum += dd * dd;
    }
    #pragma unroll
    for (int m = 32; m >= 1; m >>= 1) lsum += __shfl_xor(lsum, m, 64);
    if ((tid & 63) == 0) atomicAdd(loss_sum, lsum);
}

// ------- scan_cs: prefix over cnt -> cursor, cs_norm out, loss out -----------
__global__ __launch_bounds__(1024) void scan_cs(const int* __restrict__ cnt_i,
                                                const float* __restrict__ csize,
                                                const float* __restrict__ loss_sum,
                                                int* __restrict__ cursor,
                                                float* __restrict__ csn_out,
                                                float* __restrict__ loss_out) {
    __shared__ int   sc[1024];
    __shared__ float sf[1024];
    const int tid = threadIdx.x;
    int v[8], part = 0;
    float cv[8], fpart = 0.f;
    #pragma unroll
    for (int j = 0; j < 8; ++j) { v[j] = cnt_i[tid * 8 + j]; part += v[j]; }
    #pragma unroll
    for (int j = 0; j < 8; ++j) {
        cv[j] = 0.99f * csize[tid * 8 + j] + 0.01f * (float)v[j];
        fpart += cv[j];
    }
    sc[tid] = part;
    sf[tid] = fpart;
    __syncthreads();
    for (int off = 1; off < 1024; off <<= 1) {
        int add = (tid >= off) ? sc[tid - off] : 0;
        __syncthreads();
        sc[tid] += add;
        __syncthreads();
    }
    int run = sc[tid] - part;
    #pragma unroll
    for (int j = 0; j < 8; ++j) {
        cursor[tid * 8 + j] = run;
        run += v[j];
    }
    for (int off = 512; off >= 1; off >>= 1) {
        if (tid < off) sf[tid] += sf[tid + off];
        __syncthreads();
    }
    float denom = sf[0] + (float)(K_CODES * 1e-5);
    #pragma unroll
    for (int j = 0; j < 8; ++j) csn_out[tid * 8 + j] = (cv[j] + 1e-5f) / denom;
    if (tid == 0) *loss_out = 0.25f * (*loss_sum) * (1.0f / (float)NELEM);
}

// ------- scatter: tokens into code-sorted order, with code tags --------------
__global__ __launch_bounds__(256) void scatter_kernel(const int* __restrict__ idx_i32,
                                                      int* __restrict__ cursor,
                                                      int* __restrict__ tok_of,
                                                      int* __restrict__ code_of) {
    int t = blockIdx.x * 256 + threadIdx.x;
    int k = idx_i32[t];
    int pos = atomicAdd(&cursor[k], 1);
    tok_of[pos] = t;
    code_of[pos] = k;
}

// ------- ema_acc: balanced 64-position chunks, pipelined loads ---------------
__global__ __launch_bounds__(256) void ema_acc(const float* __restrict__ z,
                                               const float* __restrict__ z_t,
                                               const int* __restrict__ tok_of,
                                               const int* __restrict__ code_of,
                                               float* __restrict__ emao_out) {
    const int wv   = (blockIdx.x * 256 + threadIdx.x) >> 6;   // 0..511
    const int lane = threadIdx.x & 63;
    const int pos0 = wv * 64;
    const int tok  = tok_of[pos0 + lane];
    const int cod  = code_of[pos0 + lane];
    float acc = 0.f;
    #pragma unroll
    for (int g = 0; g < 8; ++g) {
        int tk[8], kk[8];
        #pragma unroll
        for (int j = 0; j < 8; ++j) {
            tk[j] = __shfl(tok, g * 8 + j, 64);
            kk[j] = __shfl(cod, g * 8 + j, 64);
        }
        float v[8];
        if (z_t) {
            #pragma unroll
            for (int j = 0; j < 8; ++j) v[j] = z_t[tk[j] * 64 + lane];
        } else {
            #pragma unroll
            for (int j = 0; j < 8; ++j)
                v[j] = z[(tk[j] >> 10) * CHW + lane * HWSZ + (tk[j] & 1023)];
        }
        int knext = (g < 7) ? __shfl(cod, g * 8 + 8, 64) : -1;
        #pragma unroll
        for (int j = 0; j < 8; ++j) {
            acc += v[j];
            int kn = (j < 7) ? kk[j + 1] : knext;
            if (kn != kk[j]) {
                atomicAdd(&emao_out[kk[j] * 64 + lane], 0.01f * acc);
                acc = 0.f;
            }
        }
    }
}

// ------- final_div: emb_out = emao / csn -------------------------------------
__global__ __launch_bounds__(256) void final_div(const float* __restrict__ emao_out,
                                                 const float* __restrict__ csn_out,
                                                 float* __restrict__ embo_out) {
    int g = blockIdx.x * 256 + threadIdx.x;
    embo_out[g] = emao_out[g] / csn_out[g >> 6];
}

extern "C" void kernel_launch(void* const* d_in, const int* in_sizes, int n_in,
                              void* d_out, int out_size, void* d_ws, size_t ws_size,
                              hipStream_t stream) {
    (void)in_sizes; (void)n_in; (void)out_size;
    const float* z     = (const float*)d_in[0];
    const float* emb   = (const float*)d_in[1];
    const float* ema_w = (const float*)d_in[2];
    const float* csize = (const float*)d_in[3];

    float* out      = (float*)d_out;
    float* zq_out   = out;
    float* loss_out = out + 2097152;
    float* idx_out  = out + 2097153;
    float* csn_out  = out + 2129921;
    float* emao_out = out + 2138113;
    float* embo_out = out + 2662401;

    char* wsb = (char*)d_ws;
    unsigned short*     blob    = (unsigned short*)(wsb);              // 2,097,152 B
    float*              eng     = (float*)(wsb + 2097152);             // 32 KB
    unsigned long long* packed  = (unsigned long long*)(wsb + 2129920);// 256 KB
    int*                code_of = (int*)(wsb + 2129920);               // aliases packed (dead after zq_loss)
    int*                idx_i32 = (int*)(wsb + 2392064);               // 128 KB
    int*                cnt_i   = (int*)(wsb + 2523136);               // 32 KB
    float*              sums    = (float*)(wsb + 2555904);             // 8 B
    int*                cursor  = (int*)(wsb + 2555920);               // 32 KB
    int*                tok_of  = (int*)(wsb + 2588688);               // 128 KB
    const size_t zt_off = 2719760;
    float* z_t = (ws_size >= zt_off + (size_t)NELEM * 4) ? (float*)(wsb + zt_off) : nullptr;

    prep_e<<<128, 256, 0, stream>>>(emb, blob, eng, packed, cnt_i, sums);
    vq_argmin<<<1024, 256, 0, stream>>>(z, blob, eng, packed);
    zq_loss<<<N_TOK / 64, 256, 0, stream>>>(z, emb, ema_w, packed, zq_out, idx_out,
                                            idx_i32, cnt_i, sums + 1, z_t, emao_out);
    scan_cs<<<1, 1024, 0, stream>>>(cnt_i, csize, sums + 1, cursor, csn_out, loss_out);
    scatter_kernel<<<N_TOK / 256, 256, 0, stream>>>(idx_i32, cursor, tok_of, code_of);
    ema_acc<<<128, 256, 0, stream>>>(z, z_t, tok_of, code_of, emao_out);
    final_div<<<K_CODES * DIM / 256, 256, 0, stream>>>(emao_out, csn_out, embo_out);
}

// Round 10
// 201.244 us; speedup vs baseline: 1.6857x; 1.0756x over previous
//
#include <hip/hip_runtime.h>
#include <float.h>

#define N_TOK   32768
#define DIM     64
#define K_CODES 8192
#define HWSZ    1024
#define CHW     65536
#define NELEM   2097152

typedef short  bf16x8 __attribute__((ext_vector_type(8)));
typedef float  f32x16 __attribute__((ext_vector_type(16)));

static __device__ __forceinline__ unsigned short f2bf(float x) {
    unsigned u = __float_as_uint(x);
    unsigned r = u + 0x7FFFu + ((u >> 16) & 1u);
    return (unsigned short)(r >> 16);
}
static __device__ __forceinline__ float bf2f(unsigned short h) {
    return __uint_as_float(((unsigned)h) << 16);
}

// ------- prep_e: emb -> frag-ordered bf16 hi/lo blob + ||e||^2 + ws init -----
// Also inits emao_out = 0.99*ema_w (must precede zq_loss's atomic accum).
__global__ __launch_bounds__(256) void prep_e(const float* __restrict__ emb,
                                              const float* __restrict__ ema_w,
                                              unsigned short* __restrict__ blob,
                                              float* __restrict__ eng,
                                              unsigned long long* __restrict__ packed,
                                              int* __restrict__ cnt_i,
                                              float* __restrict__ sums,
                                              float* __restrict__ emao_out) {
    __shared__ float part[512];
    const int gid = blockIdx.x * 256 + threadIdx.x;   // 0..32767
    packed[gid] = ~0ull;                              // init for atomicMin
    if (gid < K_CODES) cnt_i[gid] = 0;
    if (gid < 2) sums[gid] = 0.f;

    // emao init: 16 strided elements per thread, coalesced
    #pragma unroll
    for (int j = 0; j < 16; ++j) {
        int i = gid + j * 32768;
        emao_out[i] = 0.99f * ema_w[i];
    }

    int tile = blockIdx.x;
    #pragma unroll
    for (int u0 = 0; u0 < 2; ++u0) {
        int u = threadIdx.x + u0 * 256;
        int s = u >> 7, h = (u >> 6) & 1, n = u & 63;
        const float* src = emb + (tile * 64 + n) * 64 + s * 16 + h * 8;
        float4 v0 = *(const float4*)src;
        float4 v1 = *(const float4*)(src + 4);
        float x[8] = {v0.x, v0.y, v0.z, v0.w, v1.x, v1.y, v1.z, v1.w};
        unsigned short hi[8], lo[8];
        float ss = 0.f;
        #pragma unroll
        for (int j = 0; j < 8; ++j) {
            hi[j] = f2bf(x[j]);
            lo[j] = f2bf(x[j] - bf2f(hi[j]));
            ss += x[j] * x[j];
        }
        part[u] = ss;
        unsigned short* dhi = blob + (size_t)tile * 8192 + ((s * 2 + 0) * 2 + h) * 512 + n * 8;
        unsigned short* dlo = blob + (size_t)tile * 8192 + ((s * 2 + 1) * 2 + h) * 512 + n * 8;
        uint4 ph, pl;
        ph.x = (unsigned)hi[0] | ((unsigned)hi[1] << 16);
        ph.y = (unsigned)hi[2] | ((unsigned)hi[3] << 16);
        ph.z = (unsigned)hi[4] | ((unsigned)hi[5] << 16);
        ph.w = (unsigned)hi[6] | ((unsigned)hi[7] << 16);
        pl.x = (unsigned)lo[0] | ((unsigned)lo[1] << 16);
        pl.y = (unsigned)lo[2] | ((unsigned)lo[3] << 16);
        pl.z = (unsigned)lo[4] | ((unsigned)lo[5] << 16);
        pl.w = (unsigned)lo[6] | ((unsigned)lo[7] << 16);
        *(uint4*)dhi = ph;
        *(uint4*)dlo = pl;
    }
    __syncthreads();
    if (threadIdx.x < 64) {
        float s = 0.f;
        #pragma unroll
        for (int j = 0; j < 8; ++j) s += part[threadIdx.x + j * 64];
        eng[tile * 64 + threadIdx.x] = s;
    }
}

// ---------------- argmin: software-pipelined, eng-seeded acc (R4 exact) ------
__global__ __launch_bounds__(256, 3) void vq_argmin(const float* __restrict__ z,
                                                    const unsigned short* __restrict__ blob,
                                                    const float* __restrict__ eng,
                                                    unsigned long long* __restrict__ packed) {
    __shared__ __align__(16) unsigned short zh[64 * 72];
    __shared__ __align__(16) unsigned short zl[64 * 72];
    __shared__ unsigned long long red[64 * 4];

    const int tid  = threadIdx.x;
    const int lane = tid & 63;
    const int wid  = tid >> 6;           // 0..3
    const int l31  = lane & 31, h = lane >> 5;

    const int tb = blockIdx.x & 511;     // token-tile id 0..511
    const int ks = blockIdx.x >> 9;      // K split 0/1
    const int n0 = tb * 64;
    const int zbase = (n0 >> 10) * CHW + (n0 & 1023);

    // ---- stage -2*z as bf16 hi/lo (64 tokens x 64 dims) ----
    {
        int f4 = tid & 15;               // 16 float4 = 64 tokens per channel
        int c0 = tid >> 4;               // 0..15
        #pragma unroll
        for (int r = 0; r < 4; ++r) {
            int c = c0 * 4 + r;
            float4 v = *(const float4*)(z + zbase + c * HWSZ + f4 * 4);
            float x[4] = {v.x, v.y, v.z, v.w};
            #pragma unroll
            for (int e = 0; e < 4; ++e) {
                int t = f4 * 4 + e;
                float xs = -2.0f * x[e];
                unsigned short hi = f2bf(xs);
                zh[t * 72 + c] = hi;
                zl[t * 72 + c] = f2bf(xs - bf2f(hi));
            }
        }
    }
    __syncthreads();

    // ---- resident token fragments (B operand), both 32-token tiles ----
    bf16x8 T0h[4], T0l[4], T1h[4], T1l[4];
    {
        int r0 = l31;        // tile 0 token
        int r1 = 32 + l31;   // tile 1 token
        #pragma unroll
        for (int s = 0; s < 4; ++s) {
            T0h[s] = *(const bf16x8*)(&zh[r0 * 72 + s * 16 + h * 8]);
            T0l[s] = *(const bf16x8*)(&zl[r0 * 72 + s * 16 + h * 8]);
            T1h[s] = *(const bf16x8*)(&zh[r1 * 72 + s * 16 + h * 8]);
            T1l[s] = *(const bf16x8*)(&zl[r1 * 72 + s * 16 + h * 8]);
        }
    }

    const int hk0 = ks * 128 + wid;
    const unsigned short* bp = blob + (size_t)(hk0 >> 1) * 8192 + ((hk0 & 1) * 32 + l31) * 8;
    const float* ep = eng + (hk0 >> 1) * 64 + (hk0 & 1) * 32 + 4 * h;
    int scode = __builtin_amdgcn_readfirstlane((hk0 >> 1) * 64 + (hk0 & 1) * 32);

    // prologue: first tile's E frags + eng
    bf16x8 Eh[4], El[4];
    #pragma unroll
    for (int s = 0; s < 4; ++s) {
        Eh[s] = *(const bf16x8*)(bp + (4 * s + h) * 512);
        El[s] = *(const bf16x8*)(bp + (4 * s + 2 + h) * 512);
    }
    float4 g0 = *(const float4*)(ep);
    float4 g1 = *(const float4*)(ep + 8);
    float4 g2 = *(const float4*)(ep + 16);
    float4 g3 = *(const float4*)(ep + 24);

    float minv0 = FLT_MAX, minv1 = FLT_MAX;
    int   mini0 = 0,       mini1 = 0;

    for (int i = 0; i < 32; ++i) {
        // seed acc with ||e||^2 (round-2 numerics: eng is the MFMA C operand)
        f32x16 ac0, ac1;
        ac0[0]  = g0.x; ac0[1]  = g0.y; ac0[2]  = g0.z; ac0[3]  = g0.w;
        ac0[4]  = g1.x; ac0[5]  = g1.y; ac0[6]  = g1.z; ac0[7]  = g1.w;
        ac0[8]  = g2.x; ac0[9]  = g2.y; ac0[10] = g2.z; ac0[11] = g2.w;
        ac0[12] = g3.x; ac0[13] = g3.y; ac0[14] = g3.z; ac0[15] = g3.w;
        ac1 = ac0;

        // prefetch next tile's eng (g regs dead after seed)
        ep += 128;
        g0 = *(const float4*)(ep);
        g1 = *(const float4*)(ep + 8);
        g2 = *(const float4*)(ep + 16);
        g3 = *(const float4*)(ep + 24);

        __builtin_amdgcn_s_setprio(1);
        #pragma unroll
        for (int s = 0; s < 4; ++s) {
            ac0 = __builtin_amdgcn_mfma_f32_32x32x16_bf16(El[s], T0h[s], ac0, 0, 0, 0);
            ac1 = __builtin_amdgcn_mfma_f32_32x32x16_bf16(El[s], T1h[s], ac1, 0, 0, 0);
            ac0 = __builtin_amdgcn_mfma_f32_32x32x16_bf16(Eh[s], T0l[s], ac0, 0, 0, 0);
            ac1 = __builtin_amdgcn_mfma_f32_32x32x16_bf16(Eh[s], T1l[s], ac1, 0, 0, 0);
            ac0 = __builtin_amdgcn_mfma_f32_32x32x16_bf16(Eh[s], T0h[s], ac0, 0, 0, 0);
            ac1 = __builtin_amdgcn_mfma_f32_32x32x16_bf16(Eh[s], T1h[s], ac1, 0, 0, 0);
        }
        __builtin_amdgcn_s_setprio(0);

        // prefetch next tile's E frags (E regs dead once MFMAs issued)
        bp += 2 * 8192;   // hk += 4  ->  2 kt tiles of 8192 shorts
        #pragma unroll
        for (int s = 0; s < 4; ++s) {
            Eh[s] = *(const bf16x8*)(bp + (4 * s + h) * 512);
            El[s] = *(const bf16x8*)(bp + (4 * s + 2 + h) * 512);
        }

        // epilogue: acc IS the distance; min-update (cmp + 2 sel)
        #pragma unroll
        for (int r = 0; r < 16; ++r) {
            int code = scode + ((r & 3) + 8 * (r >> 2));
            if (ac0[r] < minv0) { minv0 = ac0[r]; mini0 = code; }
            if (ac1[r] < minv1) { minv1 = ac1[r]; mini1 = code; }
        }
        scode += 128;
    }
    mini0 += 4 * h;   // lane-dependent part of code, applied once
    mini1 += 4 * h;

    // ---- merge h halves (same token, disjoint code rows), then waves ----
    unsigned u0 = __float_as_uint(minv0);
    u0 = (u0 & 0x80000000u) ? ~u0 : (u0 | 0x80000000u);
    unsigned long long k0 = ((unsigned long long)u0 << 32) | (unsigned)mini0;
    unsigned u1 = __float_as_uint(minv1);
    u1 = (u1 & 0x80000000u) ? ~u1 : (u1 | 0x80000000u);
    unsigned long long k1 = ((unsigned long long)u1 << 32) | (unsigned)mini1;
    unsigned long long o0 = __shfl_xor(k0, 32, 64);
    if (o0 < k0) k0 = o0;
    unsigned long long o1 = __shfl_xor(k1, 32, 64);
    if (o1 < k1) k1 = o1;
    if (h == 0) {
        red[l31 * 4 + wid]        = k0;
        red[(32 + l31) * 4 + wid] = k1;
    }
    __syncthreads();
    if (tid < 64) {
        unsigned long long a = red[tid * 4], b = red[tid * 4 + 1];
        unsigned long long c = red[tid * 4 + 2], d = red[tid * 4 + 3];
        unsigned long long m = (b < a) ? b : a;
        if (c < m) m = c;
        if (d < m) m = d;
        atomicMin(&packed[n0 + tid], m);
    }
}

// ------- zq_loss v3: v2 + direct coalesced row-atomic emao accumulation ------
// Replaces the scatter+ema_acc machinery: avg 4 tokens/code -> contention is
// trivial, so each wave issues 16 fully-coalesced 256B atomic bursts
// (emao[idx*64+lane] += 0.01*z). z_t, tok_of, code_of, cursor all eliminated.
// idx/zq/loss paths bit-exact vs R9.
__global__ __launch_bounds__(256) void zq_loss(const float* __restrict__ z,
                                               const float* __restrict__ emb,
                                               const unsigned long long* __restrict__ packed,
                                               float* __restrict__ zq_out,
                                               float* __restrict__ idx_out,
                                               int* __restrict__ idx_i32,
                                               int* __restrict__ cnt_i,
                                               float* __restrict__ loss_sum,
                                               float* __restrict__ emao_out) {
    __shared__ float e_lds[64][68];
    __shared__ float z_lds[64][68];

    const int tid = threadIdx.x;
    const int n0  = blockIdx.x * 64;
    const int t   = tid >> 2, q = tid & 3;
    const int n   = n0 + t;
    const int w   = tid >> 6, lane = tid & 63;
    const int b   = n0 >> 10;            // whole block shares b
    const int hw0 = n0 & 1023;
    const int zb  = b * CHW + hw0;

    const int idx = (int)(packed[n] & 0xFFFFFFFFull);
    if (q == 0) {
        idx_out[n] = (float)idx;
        idx_i32[n] = idx;
        atomicAdd(&cnt_i[idx], 1);
    }
    // gather emb row -> e_lds[t][q*16..]
    {
        const float* er = emb + idx * 64 + q * 16;
        float4 e0 = *(const float4*)er,       e1 = *(const float4*)(er + 4);
        float4 e2 = *(const float4*)(er + 8), e3 = *(const float4*)(er + 12);
        *(float4*)&e_lds[t][q * 16]      = e0;
        *(float4*)&e_lds[t][q * 16 + 4]  = e1;
        *(float4*)&e_lds[t][q * 16 + 8]  = e2;
        *(float4*)&e_lds[t][q * 16 + 12] = e3;
    }
    // stage z channel-major (coalesced) -> z_lds[token][c]
    {
        const int f4 = tid & 15, c0 = tid >> 4;
        #pragma unroll
        for (int r = 0; r < 4; ++r) {
            int c = c0 * 4 + r;
            float4 v = *(const float4*)(z + zb + c * HWSZ + f4 * 4);
            z_lds[f4 * 4 + 0][c] = v.x;
            z_lds[f4 * 4 + 1][c] = v.y;
            z_lds[f4 * 4 + 2][c] = v.z;
            z_lds[f4 * 4 + 3][c] = v.w;
        }
    }
    __syncthreads();

    // emao accumulation: per wave, 16 tokens, one coalesced 256B burst each
    #pragma unroll
    for (int u = 0; u < 16; ++u) {
        int tt = w * 16 + u;
        int ix = __shfl(idx, u * 4, 64);    // lane u*4 holds token tt's idx
        atomicAdd(&emao_out[ix * 64 + lane], 0.01f * z_lds[tt][lane]);
    }

    // zq_out write: channel-major, fully coalesced; same per-element arithmetic
    {
        const int f4 = tid & 15, c0 = tid >> 4;
        #pragma unroll
        for (int r = 0; r < 4; ++r) {
            int c = c0 * 4 + r;
            float4 o;
            { float zv = z_lds[f4*4+0][c]; o.x = zv + (e_lds[f4*4+0][c] - zv); }
            { float zv = z_lds[f4*4+1][c]; o.y = zv + (e_lds[f4*4+1][c] - zv); }
            { float zv = z_lds[f4*4+2][c]; o.z = zv + (e_lds[f4*4+2][c] - zv); }
            { float zv = z_lds[f4*4+3][c]; o.w = zv + (e_lds[f4*4+3][c] - zv); }
            *(float4*)(zq_out + zb + c * HWSZ + f4 * 4) = o;
        }
    }
    // loss: per-thread order identical to R4 (c = q*16+j ascending)
    float lsum = 0.f;
    #pragma unroll
    for (int j = 0; j < 16; ++j) {
        int c = q * 16 + j;
        float dd = e_lds[t][c] - z_lds[t][c];
        lsum += dd * dd;
    }
    #pragma unroll
    for (int m = 32; m >= 1; m >>= 1) lsum += __shfl_xor(lsum, m, 64);
    if ((tid & 63) == 0) atomicAdd(loss_sum, lsum);
}

// ------- scan_cs: cs_norm + loss (int prefix scan dropped — cursor is gone) --
// Float reduction order identical to R9 -> denom bit-identical.
__global__ __launch_bounds__(1024) void scan_cs(const int* __restrict__ cnt_i,
                                                const float* __restrict__ csize,
                                                const float* __restrict__ loss_sum,
                                                float* __restrict__ csn_out,
                                                float* __restrict__ loss_out) {
    __shared__ float sf[1024];
    const int tid = threadIdx.x;
    int v[8];
    float cv[8], fpart = 0.f;
    #pragma unroll
    for (int j = 0; j < 8; ++j) v[j] = cnt_i[tid * 8 + j];
    #pragma unroll
    for (int j = 0; j < 8; ++j) {
        cv[j] = 0.99f * csize[tid * 8 + j] + 0.01f * (float)v[j];
        fpart += cv[j];
    }
    sf[tid] = fpart;
    __syncthreads();
    for (int off = 512; off >= 1; off >>= 1) {
        if (tid < off) sf[tid] += sf[tid + off];
        __syncthreads();
    }
    float denom = sf[0] + (float)(K_CODES * 1e-5);
    #pragma unroll
    for (int j = 0; j < 8; ++j) csn_out[tid * 8 + j] = (cv[j] + 1e-5f) / denom;
    if (tid == 0) *loss_out = 0.25f * (*loss_sum) * (1.0f / (float)NELEM);
}

// ------- final_div: emb_out = emao / csn -------------------------------------
__global__ __launch_bounds__(256) void final_div(const float* __restrict__ emao_out,
                                                 const float* __restrict__ csn_out,
                                                 float* __restrict__ embo_out) {
    int g = blockIdx.x * 256 + threadIdx.x;
    embo_out[g] = emao_out[g] / csn_out[g >> 6];
}

extern "C" void kernel_launch(void* const* d_in, const int* in_sizes, int n_in,
                              void* d_out, int out_size, void* d_ws, size_t ws_size,
                              hipStream_t stream) {
    (void)in_sizes; (void)n_in; (void)out_size; (void)ws_size;
    const float* z     = (const float*)d_in[0];
    const float* emb   = (const float*)d_in[1];
    const float* ema_w = (const float*)d_in[2];
    const float* csize = (const float*)d_in[3];

    float* out      = (float*)d_out;
    float* zq_out   = out;
    float* loss_out = out + 2097152;
    float* idx_out  = out + 2097153;
    float* csn_out  = out + 2129921;
    float* emao_out = out + 2138113;
    float* embo_out = out + 2662401;

    char* wsb = (char*)d_ws;
    unsigned short*     blob    = (unsigned short*)(wsb);              // 2,097,152 B
    float*              eng     = (float*)(wsb + 2097152);             // 32 KB
    unsigned long long* packed  = (unsigned long long*)(wsb + 2129920);// 256 KB
    int*                idx_i32 = (int*)(wsb + 2392064);               // 128 KB
    int*                cnt_i   = (int*)(wsb + 2523136);               // 32 KB
    float*              sums    = (float*)(wsb + 2555904);             // 8 B

    prep_e<<<128, 256, 0, stream>>>(emb, ema_w, blob, eng, packed, cnt_i, sums, emao_out);
    vq_argmin<<<1024, 256, 0, stream>>>(z, blob, eng, packed);
    zq_loss<<<N_TOK / 64, 256, 0, stream>>>(z, emb, packed, zq_out, idx_out,
                                            idx_i32, cnt_i, sums + 1, emao_out);
    scan_cs<<<1, 1024, 0, stream>>>(cnt_i, csize, sums + 1, csn_out, loss_out);
    final_div<<<K_CODES * DIM / 256, 256, 0, stream>>>(emao_out, csn_out, embo_out);
}